// Round 1
// baseline (98.168 us; speedup 1.0000x reference)
//
#include <hip/hip_runtime.h>
#include <hip/hip_bf16.h>

// Problem constants
#define B 256
#define S 256
#define H 768
#define C 150
#define H4 192              // H / 4 (float4 columns)
#define NR 406              // B + C rows for the X @ cov_inv GEMM
#define NRP 408             // padded to 8-row tiles

// ---------------------------------------------------------------------------
// K1: masked partial pooling. grid (B, 4), block 192.
// part[b][chunk][h] = sum_{s in chunk} lhs[b][s][h] * mask[b][s]
// ---------------------------------------------------------------------------
__global__ void k_pool_partial(const float* __restrict__ lhs,
                               const int* __restrict__ mask,
                               float* __restrict__ part) {
    const int b = blockIdx.x, chunk = blockIdx.y, t = threadIdx.x; // t in [0,192)
    __shared__ float msk[64];
    const int s0 = chunk * 64;
    if (t < 64) msk[t] = (float)mask[b * S + s0 + t];
    __syncthreads();

    const float4* src = (const float4*)lhs + (size_t)(b * S + s0) * H4 + t;
    float4 acc = make_float4(0.f, 0.f, 0.f, 0.f);
#pragma unroll 8
    for (int s = 0; s < 64; ++s) {
        const float m = msk[s];
        const float4 v = src[(size_t)s * H4];
        acc.x += v.x * m; acc.y += v.y * m; acc.z += v.z * m; acc.w += v.w * m;
    }
    ((float4*)part)[(size_t)(b * 4 + chunk) * H4 + t] = acc;
}

// ---------------------------------------------------------------------------
// K2: finalize pooling. grid (B), block 256.
// prelogits[b][h] = (sum_c part[b][c][h]) / max(sum_s mask[b][s], 1e-9)
// ---------------------------------------------------------------------------
__global__ void k_pool_final(const int* __restrict__ mask,
                             const float* __restrict__ part,
                             float* __restrict__ prelogits) {
    const int b = blockIdx.x, t = threadIdx.x; // 256 threads
    __shared__ float red[256];
    red[t] = (float)mask[b * S + t];
    __syncthreads();
    for (int off = 128; off > 0; off >>= 1) {
        if (t < off) red[t] += red[t + off];
        __syncthreads();
    }
    const float inv = 1.0f / fmaxf(red[0], 1e-9f);
    if (t < H4) {
        const float4* p = (const float4*)part + (size_t)b * 4 * H4 + t;
        const float4 a = p[0 * H4];
        const float4 c1 = p[1 * H4];
        const float4 c2 = p[2 * H4];
        const float4 c3 = p[3 * H4];
        float4 r;
        r.x = (a.x + c1.x + c2.x + c3.x) * inv;
        r.y = (a.y + c1.y + c2.y + c3.y) * inv;
        r.z = (a.z + c1.z + c2.z + c3.z) * inv;
        r.w = (a.w + c1.w + c2.w + c3.w) * inv;
        ((float4*)prelogits)[(size_t)b * H4 + t] = r;
    }
}

// ---------------------------------------------------------------------------
// K3: R_partial = X @ cov_inv over a k-slice. X = [prelogits; means] (406x768).
// grid (51, 4), block 192. Each block: 8 rows x 192 float4-cols, k-range 192.
// ---------------------------------------------------------------------------
__global__ void k_xcov_partial(const float* __restrict__ prelogits,
                               const float* __restrict__ means,
                               const float* __restrict__ cov,
                               float* __restrict__ part2) {
    const int rb = blockIdx.x;   // row tile 0..50
    const int ky = blockIdx.y;   // k slice 0..3
    const int t = threadIdx.x;   // 0..191
    const int k0 = ky * 192;
    __shared__ float xs[8][192];

#pragma unroll
    for (int r = 0; r < 8; ++r) {
        const int row = rb * 8 + r;
        float v = 0.f;
        if (row < B)       v = prelogits[(size_t)row * H + k0 + t];
        else if (row < NR) v = means[(size_t)(row - B) * H + k0 + t];
        xs[r][t] = v;
    }
    __syncthreads();

    float4 acc[8];
#pragma unroll
    for (int r = 0; r < 8; ++r) acc[r] = make_float4(0.f, 0.f, 0.f, 0.f);

    const float4* cov4 = (const float4*)cov + (size_t)k0 * H4 + t;
#pragma unroll 4
    for (int kk = 0; kk < 192; ++kk) {
        const float4 cv = cov4[(size_t)kk * H4];
#pragma unroll
        for (int r = 0; r < 8; ++r) {
            const float xv = xs[r][kk];
            acc[r].x += xv * cv.x; acc[r].y += xv * cv.y;
            acc[r].z += xv * cv.z; acc[r].w += xv * cv.w;
        }
    }

#pragma unroll
    for (int r = 0; r < 8; ++r) {
        const int row = rb * 8 + r;
        if (row < NR)
            ((float4*)part2)[((size_t)ky * NRP + row) * H4 + t] = acc[r];
    }
}

// ---------------------------------------------------------------------------
// K4: reduce k-slices -> R (xS rows 0..255, mS rows 256..405); compute
// t_x[b] = xS[b].prelogits[b], t_m[c] = mS[c].means[c]. grid (406), block 192.
// ---------------------------------------------------------------------------
__global__ void k_reduce_t(const float* __restrict__ prelogits,
                           const float* __restrict__ means,
                           const float* __restrict__ part2,
                           float* __restrict__ R,
                           float* __restrict__ t_x,
                           float* __restrict__ t_m) {
    const int row = blockIdx.x;  // 0..405
    const int t = threadIdx.x;   // 0..191
    const float4* p2 = (const float4*)part2;
    const float4 a = p2[((size_t)0 * NRP + row) * H4 + t];
    const float4 b2 = p2[((size_t)1 * NRP + row) * H4 + t];
    const float4 c2 = p2[((size_t)2 * NRP + row) * H4 + t];
    const float4 d2 = p2[((size_t)3 * NRP + row) * H4 + t];
    float4 r;
    r.x = a.x + b2.x + c2.x + d2.x;
    r.y = a.y + b2.y + c2.y + d2.y;
    r.z = a.z + b2.z + c2.z + d2.z;
    r.w = a.w + b2.w + c2.w + d2.w;
    ((float4*)R)[(size_t)row * H4 + t] = r;

    const float4* X4 = (row < B) ? ((const float4*)prelogits + (size_t)row * H4)
                                 : ((const float4*)means + (size_t)(row - B) * H4);
    const float4 xv = X4[t];
    float pd = r.x * xv.x + r.y * xv.y + r.z * xv.z + r.w * xv.w;

    __shared__ float red[192];
    red[t] = pd;
    __syncthreads();
    if (t < 64) {
        float v = red[t] + red[t + 64] + red[t + 128];
#pragma unroll
        for (int off = 32; off > 0; off >>= 1) v += __shfl_down(v, off, 64);
        if (t == 0) {
            if (row < B) t_x[row] = v;
            else         t_m[row - B] = v;
        }
    }
}

// ---------------------------------------------------------------------------
// K5: scores_over_tasks[c][b] = t_x[b] - 2*dot(xS[b], means[c]) + t_m[c].
// grid (C, B/4), block 256 (4 waves, one b per wave).
// ---------------------------------------------------------------------------
__global__ void k_scores(const float* __restrict__ R,
                         const float* __restrict__ means,
                         const float* __restrict__ t_x,
                         const float* __restrict__ t_m,
                         float* __restrict__ out) {
    const int c = blockIdx.x;             // 0..149
    const int w = threadIdx.x >> 6;       // wave 0..3
    const int lane = threadIdx.x & 63;
    const int b = blockIdx.y * 4 + w;

    const float4* xS4 = (const float4*)R + (size_t)b * H4;
    const float4* mu4 = (const float4*)means + (size_t)c * H4;
    float s = 0.f;
#pragma unroll
    for (int j = 0; j < 3; ++j) {
        const float4 x = xS4[lane + 64 * j];
        const float4 m = mu4[lane + 64 * j];
        s += x.x * m.x + x.y * m.y + x.z * m.z + x.w * m.w;
    }
#pragma unroll
    for (int off = 32; off > 0; off >>= 1) s += __shfl_down(s, off, 64);
    if (lane == 0)
        out[B + (size_t)c * B + b] = t_x[b] - 2.0f * s + t_m[c];
}

// ---------------------------------------------------------------------------
// K6: indices[b] = argmin_c scores[c][b]. grid (1), block 256.
// ---------------------------------------------------------------------------
__global__ void k_argmin(float* __restrict__ out) {
    const int b = threadIdx.x; // 0..255
    const float* sc = out + B;
    float best = sc[b];
    int bi = 0;
    for (int c = 1; c < C; ++c) {
        const float v = sc[(size_t)c * B + b];
        if (v < best) { best = v; bi = c; }
    }
    out[b] = (float)bi;
}

extern "C" void kernel_launch(void* const* d_in, const int* in_sizes, int n_in,
                              void* d_out, int out_size, void* d_ws, size_t ws_size,
                              hipStream_t stream) {
    const float* lhs   = (const float*)d_in[0];   // [B,S,H] f32
    const int*   mask  = (const int*)d_in[1];     // [B,S] i32
    const float* means = (const float*)d_in[2];   // [C,H] f32
    const float* cov   = (const float*)d_in[3];   // [H,H] f32
    float* out = (float*)d_out;

    char* ws = (char*)d_ws;
    // ws layout (bytes):
    float* prelogits = (float*)(ws + 0);              // B*H*4      = 786432
    float* R         = (float*)(ws + 786432);         // NRP*H*4    = 1253376 -> ends 2039808
    float* t_x       = (float*)(ws + 2039808);        // 1024
    float* t_m       = (float*)(ws + 2040832);        // 1024 -> ends 2041856
    float* part1     = (float*)(ws + 2097152);        // B*4*H*4    = 3145728 (dead after K2)
    float* part2     = (float*)(ws + 2097152);        // 4*NRP*H*4  = 5013504 -> ends 7110656 (reuses part1)
    // total ws required: ~7.2 MB

    k_pool_partial<<<dim3(B, 4), 192, 0, stream>>>(lhs, mask, part1);
    k_pool_final<<<dim3(B), 256, 0, stream>>>(mask, part1, prelogits);
    k_xcov_partial<<<dim3(51, 4), 192, 0, stream>>>(prelogits, means, cov, part2);
    k_reduce_t<<<dim3(NR), 192, 0, stream>>>(prelogits, means, part2, R, t_x, t_m);
    k_scores<<<dim3(C, B / 4), 256, 0, stream>>>(R, means, t_x, t_m, out);
    k_argmin<<<dim3(1), 256, 0, stream>>>(out);
}

// Round 2
// 73.851 us; speedup vs baseline: 1.3293x; 1.3293x over previous
//
#include <hip/hip_runtime.h>
#include <hip/hip_bf16.h>

// Problem constants
#define B 256
#define S 256
#define H 768
#define C 150
#define H4 192              // H / 4 (float4 columns)

// ws layout (bytes):
//  R        : 0        .. 786432    xS [256][768] f32
//  part1    : 786432   .. 3932160   [256][4][768] f32 pool partials
//  tx_part  : 3932160  .. 3940352   [8][256] f32 (per-colsplit t_x partials)
//  tm_part  : 3940352  .. 3945216   [8][152] f32 (per-colsplit t_m partials)
//  cntp     : 3945216  .. 3949312   [256][4] i32 (per-chunk mask counts)

// ---------------------------------------------------------------------------
// kA: blocks 0..1023  : masked pool partial for (b = bid>>2, chunk = bid&3)
//     blocks 1024..1175: t_m partial via mS-slice GEMM (8 rows x 24 f4-cols,
//                        kg-split 8 within block). Co-runs under the HBM phase.
// ---------------------------------------------------------------------------
__global__ __launch_bounds__(192) void kA(const float* __restrict__ lhs,
                                          const int* __restrict__ mask,
                                          const float* __restrict__ means,
                                          const float* __restrict__ cov,
                                          float* __restrict__ part1,
                                          int* __restrict__ cntp,
                                          float* __restrict__ tm_part) {
    const int bid = blockIdx.x;
    const int t = threadIdx.x;
    __shared__ float msk[64];
    __shared__ float xsl[8 * H];     // 24 KB
    __shared__ float red[8][3];

    if (bid < 1024) {
        // ---- pool partial ----
        const int b = bid >> 2, chunk = bid & 3, s0 = chunk * 64;
        if (t < 64) msk[t] = (float)mask[b * S + s0 + t];
        __syncthreads();
        if (t < 64) {
            int v = mask[b * S + s0 + t];
#pragma unroll
            for (int off = 32; off > 0; off >>= 1) v += __shfl_down(v, off, 64);
            if (t == 0) cntp[b * 4 + chunk] = v;
        }
        const float4* src = (const float4*)lhs + (size_t)(b * S + s0) * H4 + t;
        float4 acc = make_float4(0.f, 0.f, 0.f, 0.f);
#pragma unroll 8
        for (int s = 0; s < 64; ++s) {
            const float m = msk[s];
            const float4 v = src[(size_t)s * H4];
            acc.x += v.x * m; acc.y += v.y * m; acc.z += v.z * m; acc.w += v.w * m;
        }
        ((float4*)part1)[(size_t)(b * 4 + chunk) * H4 + t] = acc;
    } else {
        // ---- t_m partial: rows r0..r0+7 of means, f4-cols cb..cb+23 ----
        const int idx = bid - 1024;
        const int rt = idx >> 3, cs = idx & 7;
        const int r0 = rt * 8, cb = cs * 24;
        const int kg = t / 24, c4 = t % 24;   // kg 0..7 (k-slice), c4 0..23

        for (int r = 0; r < 8; ++r) {
            const int row = r0 + r;
            float4 v = make_float4(0.f, 0.f, 0.f, 0.f);
            if (row < C) v = ((const float4*)means)[(size_t)row * H4 + t];
            ((float4*)xsl)[r * H4 + t] = v;
        }
        __syncthreads();

        float4 acc[8];
#pragma unroll
        for (int r = 0; r < 8; ++r) acc[r] = make_float4(0.f, 0.f, 0.f, 0.f);
        const float4* cov4 = (const float4*)cov + cb + c4;
#pragma unroll 4
        for (int kk = 0; kk < 96; ++kk) {
            const int k = kg * 96 + kk;
            const float4 cv = cov4[(size_t)k * H4];
#pragma unroll
            for (int r = 0; r < 8; ++r) {
                const float xv = xsl[r * H + k];
                acc[r].x += xv * cv.x; acc[r].y += xv * cv.y;
                acc[r].z += xv * cv.z; acc[r].w += xv * cv.w;
            }
        }
        // t_m partial: sum over (kg, cols) of acc . mu  — all 192 threads contribute
        const int w = t >> 6;
#pragma unroll
        for (int r = 0; r < 8; ++r) {
            const float4 mu = ((float4*)xsl)[r * H4 + cb + c4];
            float pd = acc[r].x * mu.x + acc[r].y * mu.y + acc[r].z * mu.z + acc[r].w * mu.w;
#pragma unroll
            for (int off = 32; off > 0; off >>= 1) pd += __shfl_down(pd, off, 64);
            if ((t & 63) == 0) red[r][w] = pd;
        }
        __syncthreads();
        if (t < 8) {
            const int row = r0 + t;
            if (row < C) tm_part[cs * 152 + row] = red[t][0] + red[t][1] + red[t][2];
        }
    }
}

// ---------------------------------------------------------------------------
// kC: xS = prelogits @ cov (pool-finalize inlined), write R, t_x partials.
// grid 256 = 32 row-tiles x 8 col-splits; block 192 = 8 kg x 24 f4-cols.
// ---------------------------------------------------------------------------
__global__ __launch_bounds__(192) void kC(const float* __restrict__ part1,
                                          const int* __restrict__ cntp,
                                          const float* __restrict__ cov,
                                          float* __restrict__ R,
                                          float* __restrict__ tx_part) {
    const int rt = blockIdx.x >> 3, cs = blockIdx.x & 7;
    const int r0 = rt * 8, cb = cs * 24;
    const int t = threadIdx.x;
    const int kg = t / 24, c4 = t % 24;
    __shared__ float xsl[8 * H];         // pooled rows (prelogits), 24 KB
    __shared__ float4 red2[8][24];

    for (int r = 0; r < 8; ++r) {
        const int row = r0 + r;
        const int cnt = cntp[row * 4] + cntp[row * 4 + 1] + cntp[row * 4 + 2] + cntp[row * 4 + 3];
        const float inv = 1.0f / fmaxf((float)cnt, 1e-9f);
        const float4* p = (const float4*)part1 + (size_t)row * 4 * H4 + t;
        const float4 a = p[0], b2 = p[H4], c2 = p[2 * H4], d2 = p[3 * H4];
        float4 v;
        v.x = (a.x + b2.x + c2.x + d2.x) * inv;
        v.y = (a.y + b2.y + c2.y + d2.y) * inv;
        v.z = (a.z + b2.z + c2.z + d2.z) * inv;
        v.w = (a.w + b2.w + c2.w + d2.w) * inv;
        ((float4*)xsl)[r * H4 + t] = v;
    }
    __syncthreads();

    float4 acc[8];
#pragma unroll
    for (int r = 0; r < 8; ++r) acc[r] = make_float4(0.f, 0.f, 0.f, 0.f);
    const float4* cov4 = (const float4*)cov + cb + c4;
#pragma unroll 4
    for (int kk = 0; kk < 96; ++kk) {
        const int k = kg * 96 + kk;
        const float4 cv = cov4[(size_t)k * H4];
#pragma unroll
        for (int r = 0; r < 8; ++r) {
            const float xv = xsl[r * H + k];
            acc[r].x += xv * cv.x; acc[r].y += xv * cv.y;
            acc[r].z += xv * cv.z; acc[r].w += xv * cv.w;
        }
    }

    float pdr[8];
#pragma unroll
    for (int r = 0; r < 8; ++r) pdr[r] = 0.f;
    for (int r = 0; r < 8; ++r) {
        red2[kg][c4] = acc[r];
        __syncthreads();
        if (kg == 0) {
            float4 s = red2[0][c4];
#pragma unroll
            for (int g = 1; g < 8; ++g) {
                const float4 q = red2[g][c4];
                s.x += q.x; s.y += q.y; s.z += q.z; s.w += q.w;
            }
            ((float4*)R)[(size_t)(r0 + r) * H4 + cb + c4] = s;
            const float4 xv = ((float4*)xsl)[r * H4 + cb + c4];
            pdr[r] = s.x * xv.x + s.y * xv.y + s.z * xv.z + s.w * xv.w;
        }
        __syncthreads();
    }
    if (t < 64) {
#pragma unroll
        for (int r = 0; r < 8; ++r) {
            float v = (t < 24) ? pdr[r] : 0.f;
#pragma unroll
            for (int off = 32; off > 0; off >>= 1) v += __shfl_down(v, off, 64);
            if (t == 0) tx_part[cs * 256 + r0 + r] = v;
        }
    }
}

// ---------------------------------------------------------------------------
// kD: scores + argmin, one block per b. 8 waves; wave w handles c = w, w+8, ...
// xS row in registers; dot via shfl reduce; tie-aware argmin.
// ---------------------------------------------------------------------------
__global__ __launch_bounds__(512) void kD(const float* __restrict__ R,
                                          const float* __restrict__ means,
                                          const float* __restrict__ tx_part,
                                          const float* __restrict__ tm_part,
                                          float* __restrict__ out) {
    const int b = blockIdx.x;
    const int t = threadIdx.x, w = t >> 6, lane = t & 63;
    __shared__ float tml[C];
    __shared__ float bw[8];
    __shared__ int bi[8];

    if (t < C) {
        float tm = 0.f;
#pragma unroll
        for (int j = 0; j < 8; ++j) tm += tm_part[j * 152 + t];
        tml[t] = tm;
    }
    const float4* xr = (const float4*)R + (size_t)b * H4;
    const float4 x0 = xr[lane], x1 = xr[lane + 64], x2 = xr[lane + 128];
    float tx = 0.f;
#pragma unroll
    for (int j = 0; j < 8; ++j) tx += tx_part[j * 256 + b];
    __syncthreads();

    float bestv = INFINITY;
    int besti = 0;
    for (int c = w; c < C; c += 8) {
        const float4* mu = (const float4*)means + (size_t)c * H4;
        const float4 m0 = mu[lane], m1 = mu[lane + 64], m2 = mu[lane + 128];
        float d = x0.x * m0.x + x0.y * m0.y + x0.z * m0.z + x0.w * m0.w
                + x1.x * m1.x + x1.y * m1.y + x1.z * m1.z + x1.w * m1.w
                + x2.x * m2.x + x2.y * m2.y + x2.z * m2.z + x2.w * m2.w;
#pragma unroll
        for (int off = 32; off > 0; off >>= 1) d += __shfl_down(d, off, 64);
        if (lane == 0) {
            const float sc = tx - 2.0f * d + tml[c];
            out[B + (size_t)c * B + b] = sc;
            if (sc < bestv || (sc == bestv && c < besti)) { bestv = sc; besti = c; }
        }
    }
    if (lane == 0) { bw[w] = bestv; bi[w] = besti; }
    __syncthreads();
    if (t == 0) {
        float bv = bw[0];
        int bj = bi[0];
#pragma unroll
        for (int j = 1; j < 8; ++j)
            if (bw[j] < bv || (bw[j] == bv && bi[j] < bj)) { bv = bw[j]; bj = bi[j]; }
        out[b] = (float)bj;
    }
}

extern "C" void kernel_launch(void* const* d_in, const int* in_sizes, int n_in,
                              void* d_out, int out_size, void* d_ws, size_t ws_size,
                              hipStream_t stream) {
    const float* lhs   = (const float*)d_in[0];   // [B,S,H] f32
    const int*   mask  = (const int*)d_in[1];     // [B,S] i32
    const float* means = (const float*)d_in[2];   // [C,H] f32
    const float* cov   = (const float*)d_in[3];   // [H,H] f32
    float* out = (float*)d_out;

    char* ws = (char*)d_ws;
    float* R       = (float*)(ws + 0);
    float* part1   = (float*)(ws + 786432);
    float* tx_part = (float*)(ws + 3932160);
    float* tm_part = (float*)(ws + 3940352);
    int*   cntp    = (int*)  (ws + 3945216);

    kA<<<dim3(1024 + 152), 192, 0, stream>>>(lhs, mask, means, cov, part1, cntp, tm_part);
    kC<<<dim3(256), 192, 0, stream>>>(part1, cntp, cov, R, tx_part);
    kD<<<dim3(256), 512, 0, stream>>>(R, means, tx_part, tm_part, out);
}